// Round 1
// baseline (1749.966 us; speedup 1.0000x reference)
//
#include <hip/hip_runtime.h>
#include <stdint.h>

#define T_SEQ 2048
#define C_DIM 4096
#define NHEAD 32
#define NKV 8
#define HD 128
#define HIDDEN 11008
#define QKV_W (C_DIM + 2 * NKV * HD)  // 6144

typedef float f32x4 __attribute__((ext_vector_type(4)));
typedef __bf16 bf16x8 __attribute__((ext_vector_type(8)));
typedef __attribute__((address_space(1))) const void* gptr_t;
typedef __attribute__((address_space(3))) void* lptr_t;

__device__ __forceinline__ unsigned short f2bf(float f) {
  unsigned u = __float_as_uint(f);
  u += 0x7fffu + ((u >> 16) & 1u);
  return (unsigned short)(u >> 16);
}
__device__ __forceinline__ float bf2f(unsigned short h) {
  return __uint_as_float(((unsigned)h) << 16);
}

// ---------------------------------------------------------------------------
// bf16 GEMM: C[M,N] = A[M,K] @ B[N,K]^T (+ optional fp32 residual).
// 128x128 tile, BK=64, 4 waves, 4x4 MFMA 16x16x32/wave, global_load_lds w=16.
// XOR swizzle (verified: SQ_LDS_BANK_CONFLICT -> 0): LDS chunk p of row r
// holds global chunk p^(r&7); applied on the global source address at staging.
// ---------------------------------------------------------------------------
template <typename OutT, bool RESID, int LDA, int LDB, int LDC, int K,
          long SAZ, long SBZ, int BZSH, long SCZ>
__global__ __launch_bounds__(256) void gemm_bt(
    const unsigned short* __restrict__ A, const unsigned short* __restrict__ B,
    OutT* __restrict__ C, const float* __restrict__ R)
{
  const int z = blockIdx.z;
  A += (long)z * SAZ;
  B += (long)(z >> BZSH) * SBZ;
  C += (long)z * SCZ;
  const float* Rz = RESID ? (R + (long)z * SCZ) : nullptr;

  __shared__ unsigned short lA[128 * 64];
  __shared__ unsigned short lB[128 * 64];

  const int t     = threadIdx.x;
  const int lane  = t & 63;
  const int srow  = t >> 3;                          // 0..31
  const int scolL = (t & 7) << 3;                    // LDS chunk (fixed by HW)
  const int scolG = (((t & 7) ^ (srow & 7)) << 3);   // swizzled global chunk
  const int wave  = t >> 6;
  const int wr    = (wave >> 1) << 6;
  const int wc    = (wave & 1) << 6;
  const int m16   = lane & 15;
  const int quad  = lane >> 4;
  const int rl    = lane & 7;                        // fragment row & 7
  const int c0    = ((quad ^ rl) << 3);              // kk=0 swizzled column
  const int c1    = (((4 + quad) ^ rl) << 3);        // kk=32 swizzled column

  const long tileM = (long)blockIdx.y * 128;
  const long tileN = (long)blockIdx.x * 128;

  f32x4 acc[4][4] = {};

  const unsigned short* Aptr = A + (tileM + srow) * LDA + scolG;
  const unsigned short* Bptr = B + (tileN + srow) * LDB + scolG;

  for (int k0 = 0; k0 < K; k0 += 64) {
#pragma unroll
    for (int s = 0; s < 4; ++s) {
      __builtin_amdgcn_global_load_lds((gptr_t)(Aptr + s * 32 * LDA),
                                       (lptr_t)&lA[(s * 32 + srow) * 64 + scolL], 16, 0, 0);
      __builtin_amdgcn_global_load_lds((gptr_t)(Bptr + s * 32 * LDB),
                                       (lptr_t)&lB[(s * 32 + srow) * 64 + scolL], 16, 0, 0);
    }
    Aptr += 64;
    Bptr += 64;
    __syncthreads();
    {
      bf16x8 af[4], bfr[4];
#pragma unroll
      for (int i = 0; i < 4; ++i)
        af[i] = *(const bf16x8*)&lA[(wr + i * 16 + m16) * 64 + c0];
#pragma unroll
      for (int j = 0; j < 4; ++j)
        bfr[j] = *(const bf16x8*)&lB[(wc + j * 16 + m16) * 64 + c0];
#pragma unroll
      for (int i = 0; i < 4; ++i)
#pragma unroll
        for (int j = 0; j < 4; ++j)
          acc[i][j] = __builtin_amdgcn_mfma_f32_16x16x32_bf16(af[i], bfr[j], acc[i][j], 0, 0, 0);
    }
    {
      bf16x8 af[4], bfr[4];
#pragma unroll
      for (int i = 0; i < 4; ++i)
        af[i] = *(const bf16x8*)&lA[(wr + i * 16 + m16) * 64 + c1];
#pragma unroll
      for (int j = 0; j < 4; ++j)
        bfr[j] = *(const bf16x8*)&lB[(wc + j * 16 + m16) * 64 + c1];
#pragma unroll
      for (int i = 0; i < 4; ++i)
#pragma unroll
        for (int j = 0; j < 4; ++j)
          acc[i][j] = __builtin_amdgcn_mfma_f32_16x16x32_bf16(af[i], bfr[j], acc[i][j], 0, 0, 0);
    }
    __syncthreads();
  }

  // C/D layout (verified): col = lane&15, row = (lane>>4)*4 + reg
#pragma unroll
  for (int i = 0; i < 4; ++i) {
#pragma unroll
    for (int j = 0; j < 4; ++j) {
      const long row = tileM + wr + i * 16 + quad * 4;
      const long col = tileN + wc + j * 16 + m16;
#pragma unroll
      for (int r = 0; r < 4; ++r) {
        const long off = (row + r) * (long)LDC + col;
        float v = acc[i][j][r];
        if constexpr (RESID) v += Rz[off];
        if constexpr (sizeof(OutT) == 2) C[off] = f2bf(v);
        else                             C[off] = v;
      }
    }
  }
}

// ---------------------------------------------------------------------------
// Fused causal flash attention (replaces scores GEMM + softmax + PV GEMM).
// Grid: 512 blocks = (head 0..31) x (128-row Q tile 0..15). 4 waves x 32 rows.
// Per KV tile (KVBLK=64): stage K[64][128] and V^T[128][64] to LDS (chunk-XOR
// swizzled via pre-swizzled global source), S = Q@K^T via MFMA, online-softmax
// in registers (row is wave-local: stats per (i,quad,r), reduce over m16 lanes
// only), P round-trips through a wave-private swizzled LDS tile, PV accumulates
// O in registers. Q is hoisted to registers once (8x bf16x8 per thread).
// LDS 48 KB -> 3 blocks/CU co-residency hides staging latency.
// ---------------------------------------------------------------------------
__global__ __launch_bounds__(256) void flash_attn(
    const unsigned short* __restrict__ qkvb, const unsigned short* __restrict__ vt,
    unsigned short* __restrict__ attn)
{
  __shared__ unsigned short lK[64 * 128];   // [kv 64][d 128], 16 chunks/row, low3 XOR swz
  __shared__ unsigned short lV[128 * 64];   // [d 128][kv 64], 8 chunks/row, XOR swz
  __shared__ unsigned short lP[128 * 64];   // [q 128][kv 64], 8 chunks/row, XOR swz

  const int id   = blockIdx.x;
  const int head = id >> 4;
  int qb = id & 15;
  if (head & 1) qb = 15 - qb;          // pair big/small causal tiles across CUs
  const int kvh  = head >> 2;
  const long qOFF = (long)head * HD;
  const long kOFF = C_DIM + (long)kvh * HD;
  const int  vBase = kvh * HD;

  const int t    = threadIdx.x;
  const int lane = t & 63;
  const int w    = t >> 6;             // wave: q rows w*32 .. w*32+31
  const int m16  = lane & 15;
  const int quad = lane >> 4;
  const int rl   = lane & 7;

  const int qBase = qb * 128;

  // Q fragments hoisted: rows (qBase + w*32 + i*16 + m16), k-window kc (d 32-chunks)
  bf16x8 qf[2][4];
#pragma unroll
  for (int i = 0; i < 2; ++i)
#pragma unroll
    for (int kc = 0; kc < 4; ++kc)
      qf[i][kc] = *(const bf16x8*)&qkvb[(long)(qBase + w * 32 + i * 16 + m16) * QKV_W
                                        + qOFF + kc * 32 + quad * 8];

  f32x4 accO[2][8] = {};
  float mrow[2][4], lrow[2][4];
#pragma unroll
  for (int i = 0; i < 2; ++i)
#pragma unroll
    for (int r = 0; r < 4; ++r) { mrow[i][r] = -INFINITY; lrow[i][r] = 0.f; }

  const int nkv = 2 * qb + 2;          // causal: KV tiles 0 .. 2qb+1
  const int sKrow = t >> 4;            // K staging: row = l*16 + sKrow, chunk t&15
  const int cK    = t & 15;
  const int sVrow = t >> 3;            // V staging: row = l*32 + sVrow, chunk t&7
  const int cV    = t & 7;
  const float scale = 0.08838834764831845f;

  for (int kb = 0; kb < nkv; ++kb) {
    // --- stage K tile (16 KB) and V tile (16 KB); LDS dest linear, source pre-swizzled
#pragma unroll
    for (int l = 0; l < 4; ++l) {
      const int row = l * 16 + sKrow;
      const int cG  = (cK & 8) | ((cK & 7) ^ (row & 7));
      __builtin_amdgcn_global_load_lds(
          (gptr_t)&qkvb[(long)(kb * 64 + row) * QKV_W + kOFF + cG * 8],
          (lptr_t)&lK[row * 128 + cK * 8], 16, 0, 0);
    }
#pragma unroll
    for (int l = 0; l < 4; ++l) {
      const int row = l * 32 + sVrow;
      const int cG  = cV ^ (row & 7);
      __builtin_amdgcn_global_load_lds(
          (gptr_t)&vt[(long)(vBase + row) * T_SEQ + kb * 64 + cG * 8],
          (lptr_t)&lV[row * 64 + cV * 8], 16, 0, 0);
    }
    __syncthreads();

    // --- S = Q @ K^T : per wave 32x64, K window kc*32
    f32x4 accS[2][4] = {};
#pragma unroll
    for (int kc = 0; kc < 4; ++kc) {
      bf16x8 bk[4];
#pragma unroll
      for (int j = 0; j < 4; ++j) {
        const int c  = kc * 4 + quad;
        const int cl = (c & 8) | ((c & 7) ^ rl);
        bk[j] = *(const bf16x8*)&lK[(j * 16 + m16) * 128 + cl * 8];
      }
#pragma unroll
      for (int i = 0; i < 2; ++i)
#pragma unroll
        for (int j = 0; j < 4; ++j)
          accS[i][j] = __builtin_amdgcn_mfma_f32_16x16x32_bf16(qf[i][kc], bk[j], accS[i][j], 0, 0, 0);
    }

    // --- online softmax (rows wave-local; stats replicated across m16 lanes)
    const bool diag = (kb >= 2 * qb);
    float fac[2][4];
#pragma unroll
    for (int i = 0; i < 2; ++i) {
#pragma unroll
      for (int r = 0; r < 4; ++r) {
        float mx = -INFINITY;
#pragma unroll
        for (int j = 0; j < 4; ++j) {
          float v = accS[i][j][r] * scale;
          if (diag) {
            const int grow = qBase + w * 32 + i * 16 + quad * 4 + r;
            const int gcol = kb * 64 + j * 16 + m16;
            if (gcol > grow) v = -INFINITY;
          }
          accS[i][j][r] = v;
          mx = fmaxf(mx, v);
        }
        mx = fmaxf(mx, __shfl_xor(mx, 1));
        mx = fmaxf(mx, __shfl_xor(mx, 2));
        mx = fmaxf(mx, __shfl_xor(mx, 4));
        mx = fmaxf(mx, __shfl_xor(mx, 8));
        const float mc = fmaxf(mrow[i][r], mx);
        fac[i][r] = __expf(mrow[i][r] - mc);   // first iter: exp(-inf)=0
        mrow[i][r] = mc;
        float s = 0.f;
#pragma unroll
        for (int j = 0; j < 4; ++j) {
          const float e = __expf(accS[i][j][r] - mc);  // masked: exp(-inf)=0
          accS[i][j][r] = e;
          s += e;
        }
        s += __shfl_xor(s, 1);
        s += __shfl_xor(s, 2);
        s += __shfl_xor(s, 4);
        s += __shfl_xor(s, 8);
        lrow[i][r] = lrow[i][r] * fac[i][r] + s;
      }
    }

    // --- rescale O by exp(m_old - m_new)
#pragma unroll
    for (int i = 0; i < 2; ++i)
#pragma unroll
      for (int dj = 0; dj < 8; ++dj)
#pragma unroll
        for (int r = 0; r < 4; ++r)
          accO[i][dj][r] *= fac[i][r];

    // --- write P (bf16) to wave-private LDS region (same XOR swizzle as GEMM tiles)
#pragma unroll
    for (int i = 0; i < 2; ++i) {
#pragma unroll
      for (int j = 0; j < 4; ++j) {
        const int chunkG = j * 2 + (m16 >> 3);
#pragma unroll
        for (int r = 0; r < 4; ++r) {
          const int row = w * 32 + i * 16 + quad * 4 + r;
          lP[row * 64 + ((chunkG ^ (row & 7)) << 3) + (m16 & 7)] = f2bf(accS[i][j][r]);
        }
      }
    }
    // ensure same-wave cross-lane LDS writes land before fragment reads
    asm volatile("s_waitcnt lgkmcnt(0)" ::: "memory");

    // --- O += P @ V (A from lP, B from lV; K window kk*32 over 64 kv)
#pragma unroll
    for (int kk = 0; kk < 2; ++kk) {
      const int c = ((kk * 4 + quad) ^ rl) << 3;
      bf16x8 pa[2];
#pragma unroll
      for (int i = 0; i < 2; ++i)
        pa[i] = *(const bf16x8*)&lP[(w * 32 + i * 16 + m16) * 64 + c];
#pragma unroll
      for (int dj = 0; dj < 8; ++dj) {
        const bf16x8 vb = *(const bf16x8*)&lV[(dj * 16 + m16) * 64 + c];
#pragma unroll
        for (int i = 0; i < 2; ++i)
          accO[i][dj] = __builtin_amdgcn_mfma_f32_16x16x32_bf16(pa[i], vb, accO[i][dj], 0, 0, 0);
      }
    }
    __syncthreads();   // protect lK/lV before next stage
  }

  // --- epilogue: O /= l, write attn[q][head*128 + d]
  float inv[2][4];
#pragma unroll
  for (int i = 0; i < 2; ++i)
#pragma unroll
    for (int r = 0; r < 4; ++r) inv[i][r] = 1.f / lrow[i][r];
#pragma unroll
  for (int i = 0; i < 2; ++i) {
#pragma unroll
    for (int dj = 0; dj < 8; ++dj) {
#pragma unroll
      for (int r = 0; r < 4; ++r) {
        const long row = qBase + w * 32 + i * 16 + quad * 4 + r;
        attn[row * C_DIM + head * HD + dj * 16 + m16] = f2bf(accO[i][dj][r] * inv[i][r]);
      }
    }
  }
}

// ---------------------------------------------------------------------------
__global__ __launch_bounds__(256) void rmsnorm_kernel(
    const float* __restrict__ x, const float* __restrict__ w,
    unsigned short* __restrict__ out)
{
  const int row = blockIdx.x;
  const int t = threadIdx.x;
  const float4* xr = (const float4*)(x + (long)row * C_DIM);
  float4 xv[4];
  float s = 0.f;
#pragma unroll
  for (int i = 0; i < 4; ++i) {
    float4 a = xr[t * 4 + i];
    xv[i] = a;
    s += a.x * a.x + a.y * a.y + a.z * a.z + a.w * a.w;
  }
#pragma unroll
  for (int off = 32; off > 0; off >>= 1) s += __shfl_down(s, off);
  __shared__ float red[4];
  if ((t & 63) == 0) red[t >> 6] = s;
  __syncthreads();
  const float inv = rsqrtf((red[0] + red[1] + red[2] + red[3]) * (1.f / C_DIM) + 1e-6f);
  const float4* wr4 = (const float4*)w;
  ushort4* o = (ushort4*)(out + (long)row * C_DIM);
#pragma unroll
  for (int i = 0; i < 4; ++i) {
    float4 a = xv[i];
    float4 ww = wr4[t * 4 + i];
    ushort4 r;
    r.x = f2bf(a.x * inv * ww.x); r.y = f2bf(a.y * inv * ww.y);
    r.z = f2bf(a.z * inv * ww.z); r.w = f2bf(a.w * inv * ww.w);
    o[t * 4 + i] = r;
  }
}

// fp32 -> bf16, 4 elements/thread, grid exact (n % 1024 == 0)
__global__ __launch_bounds__(256) void cvt_kernel(
    const float* __restrict__ in, unsigned short* __restrict__ out)
{
  const long i = (long)blockIdx.x * 256 + threadIdx.x;
  float4 f = ((const float4*)in)[i];
  ushort4 r;
  r.x = f2bf(f.x); r.y = f2bf(f.y); r.z = f2bf(f.z); r.w = f2bf(f.w);
  ((ushort4*)out)[i] = r;
}

// RoPE over qkvb rows (row stride QKV_W), head columns start at COFF
template <int NHd, int COFF>
__global__ __launch_bounds__(256) void rope_kernel(
    unsigned short* tq, const float* __restrict__ cp, const float* __restrict__ sp)
{
  constexpr int SH = (NHd == 32) ? 5 : 3;
  const long idx = (long)blockIdx.x * 256 + threadIdx.x;  // over T*NHd*64
  const int i = (int)(idx & 63);
  const long rest = idx >> 6;
  const int h = (int)(rest & (NHd - 1));
  const int t = (int)(rest >> SH);
  const long base = (long)t * QKV_W + COFF + h * HD + 2 * i;
  const float re = bf2f(tq[base]);
  const float im = bf2f(tq[base + 1]);
  const float c = cp[t * 64 + i];
  const float s = sp[t * 64 + i];
  tq[base]     = f2bf(re * c - im * s);
  tq[base + 1] = f2bf(re * s + im * c);
}

// vt[kvd][t] = qkvb[t][5120 + kvd]   (kvd in [0,1024), t in [0,2048))
__global__ __launch_bounds__(256) void transpose_v(
    const unsigned short* __restrict__ qkvb, unsigned short* __restrict__ vt)
{
  const long idx = (long)blockIdx.x * 256 + threadIdx.x;
  const int t = (int)(idx & 2047);
  const int kvd = (int)(idx >> 11);
  vt[idx] = qkvb[(long)t * QKV_W + (C_DIM + NKV * HD) + kvd];
}

// h = silu(g1) * g3, 4 elements/thread
__global__ __launch_bounds__(256) void silu_mul_kernel(
    const unsigned short* __restrict__ g1, const unsigned short* __restrict__ g3,
    unsigned short* __restrict__ h)
{
  const long i = (long)blockIdx.x * 256 + threadIdx.x;
  ushort4 a4 = ((const ushort4*)g1)[i];
  ushort4 b4 = ((const ushort4*)g3)[i];
  ushort4 r;
  { float a = bf2f(a4.x), b = bf2f(b4.x); r.x = f2bf(a / (1.f + __expf(-a)) * b); }
  { float a = bf2f(a4.y), b = bf2f(b4.y); r.y = f2bf(a / (1.f + __expf(-a)) * b); }
  { float a = bf2f(a4.z), b = bf2f(b4.z); r.z = f2bf(a / (1.f + __expf(-a)) * b); }
  { float a = bf2f(a4.w), b = bf2f(b4.w); r.w = f2bf(a / (1.f + __expf(-a)) * b); }
  ((ushort4*)h)[i] = r;
}

// ---------------------------------------------------------------------------
extern "C" void kernel_launch(void* const* d_in, const int* in_sizes, int n_in,
                              void* d_out, int out_size, void* d_ws, size_t ws_size,
                              hipStream_t stream) {
  const float* x    = (const float*)d_in[0];
  const float* fcos = (const float*)d_in[2];
  const float* fsin = (const float*)d_in[3];
  const float* wq   = (const float*)d_in[5];
  const float* wk   = (const float*)d_in[6];
  const float* wv   = (const float*)d_in[7];
  const float* wo   = (const float*)d_in[8];
  const float* w1   = (const float*)d_in[9];
  const float* w2   = (const float*)d_in[10];
  const float* w3   = (const float*)d_in[11];
  const float* ln1  = (const float*)d_in[12];
  const float* ln2  = (const float*)d_in[13];
  float* out = (float*)d_out;  // also x_mid (attention residual output)

  char* p = (char*)d_ws;
  auto alloc = [&](size_t bytes) { char* r = p; p += (bytes + 255) & ~(size_t)255; return r; };
  unsigned short* Wb   = (unsigned short*)alloc((size_t)HIDDEN * C_DIM * 2);  // 90.2 MB
  unsigned short* xn   = (unsigned short*)alloc((size_t)T_SEQ * C_DIM * 2);
  unsigned short* qkvb = (unsigned short*)alloc((size_t)T_SEQ * QKV_W * 2);   // q|k|v packed per row
  unsigned short* vt   = (unsigned short*)alloc((size_t)T_SEQ * 1024 * 2);
  unsigned short* attn = (unsigned short*)alloc((size_t)T_SEQ * C_DIM * 2);
  // FFN scratch (shared region; attention no longer materializes scores)
  const size_t ffnB = (size_t)T_SEQ * C_DIM * 2 + 3ULL * T_SEQ * HIDDEN * 2;  // 152 MB
  char* regC = alloc(ffnB);
  unsigned short* xn2 = (unsigned short*)regC;
  unsigned short* g1  = (unsigned short*)(regC + (size_t)T_SEQ * C_DIM * 2);
  unsigned short* g3  = (unsigned short*)(regC + (size_t)T_SEQ * C_DIM * 2 + (size_t)T_SEQ * HIDDEN * 2);
  unsigned short* hb  = (unsigned short*)(regC + (size_t)T_SEQ * C_DIM * 2 + 2ULL * T_SEQ * HIDDEN * 2);

  // 1) xn = rmsnorm(x)
  rmsnorm_kernel<<<T_SEQ, 256, 0, stream>>>(x, ln1, xn);

  // 2) fused QKV projection: Wb rows = [wq(4096) | wk(1024) | wv(1024)]
  cvt_kernel<<<(C_DIM * C_DIM) / 1024, 256, 0, stream>>>(wq, Wb);
  cvt_kernel<<<(NKV * HD * C_DIM) / 1024, 256, 0, stream>>>(wk, Wb + (size_t)C_DIM * C_DIM);
  cvt_kernel<<<(NKV * HD * C_DIM) / 1024, 256, 0, stream>>>(wv, Wb + (size_t)(C_DIM + NKV * HD) * C_DIM);
  gemm_bt<unsigned short, false, C_DIM, C_DIM, QKV_W, C_DIM, 0, 0, 0, 0>
      <<<dim3(QKV_W / 128, T_SEQ / 128, 1), 256, 0, stream>>>(xn, Wb, qkvb, nullptr);

  // 3) RoPE q (cols 0..4095) and k (cols 4096..5119); transpose v
  rope_kernel<NHEAD, 0><<<(T_SEQ * NHEAD * 64) / 256, 256, 0, stream>>>(qkvb, fcos, fsin);
  rope_kernel<NKV, C_DIM><<<(T_SEQ * NKV * 64) / 256, 256, 0, stream>>>(qkvb, fcos, fsin);
  transpose_v<<<(T_SEQ * 1024) / 256, 256, 0, stream>>>(qkvb, vt);

  // 4) fused flash attention (no materialized scores)
  flash_attn<<<NHEAD * 16, 256, 0, stream>>>(qkvb, vt, attn);

  // 5) out = x + attn @ wo^T
  cvt_kernel<<<(C_DIM * C_DIM) / 1024, 256, 0, stream>>>(wo, Wb);
  gemm_bt<float, true, C_DIM, C_DIM, C_DIM, C_DIM, 0, 0, 0, 0>
      <<<dim3(C_DIM / 128, T_SEQ / 128, 1), 256, 0, stream>>>(attn, Wb, out, x);

  // 6) FFN
  rmsnorm_kernel<<<T_SEQ, 256, 0, stream>>>(out, ln2, xn2);
  cvt_kernel<<<((size_t)HIDDEN * C_DIM) / 1024, 256, 0, stream>>>(w1, Wb);
  gemm_bt<unsigned short, false, C_DIM, C_DIM, HIDDEN, C_DIM, 0, 0, 0, 0>
      <<<dim3(HIDDEN / 128, T_SEQ / 128, 1), 256, 0, stream>>>(xn2, Wb, g1, nullptr);
  cvt_kernel<<<((size_t)HIDDEN * C_DIM) / 1024, 256, 0, stream>>>(w3, Wb);
  gemm_bt<unsigned short, false, C_DIM, C_DIM, HIDDEN, C_DIM, 0, 0, 0, 0>
      <<<dim3(HIDDEN / 128, T_SEQ / 128, 1), 256, 0, stream>>>(xn2, Wb, g3, nullptr);
  silu_mul_kernel<<<((size_t)T_SEQ * HIDDEN) / 1024, 256, 0, stream>>>(g1, g3, hb);
  cvt_kernel<<<((size_t)C_DIM * HIDDEN) / 1024, 256, 0, stream>>>(w2, Wb);
  gemm_bt<float, true, HIDDEN, HIDDEN, C_DIM, HIDDEN, 0, 0, 0, 0>
      <<<dim3(C_DIM / 128, T_SEQ / 128, 1), 256, 0, stream>>>(hb, Wb, out, out);
}